// Round 10
// baseline (299.212 us; speedup 1.0000x reference)
//
#include <hip/hip_runtime.h>
#include <hip/hip_bf16.h>
#include <math.h>

// Problem constants
#define B_ 512
#define L_ 256
#define D_ 256
#define V_ 100000
#define O_ 1000

typedef __attribute__((ext_vector_type(8))) short short8;
typedef __attribute__((ext_vector_type(4))) float f32x4;

static __device__ __forceinline__ unsigned short f2bf(float f) {
    union { float f; unsigned u; } v; v.f = f;
    unsigned r = v.u + 0x7FFFu + ((v.u >> 16) & 1u);   // RNE (inputs are finite)
    return (unsigned short)(r >> 16);
}
static __device__ __forceinline__ float bf2f(unsigned short u) {
    union { unsigned u; float f; } v; v.u = ((unsigned)u) << 16;
    return v.f;
}
// HW packed f32->bf16 (RNE), 2 values per instruction (T12 recipe; no builtin on gfx950)
static __device__ __forceinline__ unsigned cvtpk(float lo, float hi) {
    unsigned r;
    asm("v_cvt_pk_bf16_f32 %0, %1, %2" : "=v"(r) : "v"(lo), "v"(hi));
    return r;
}
static __device__ __forceinline__ short8 pack8c(float4 a, float4 c) {
    union { unsigned u[4]; short8 s; } o;
    o.u[0] = cvtpk(a.x, a.y); o.u[1] = cvtpk(a.z, a.w);
    o.u[2] = cvtpk(c.x, c.y); o.u[3] = cvtpk(c.z, c.w);
    return o.s;
}
// fred bank-spread swizzle (valid as fsw(base)+j, j<4, base%4==0)
static __device__ __forceinline__ int fsw(int d) { return d ^ (((d >> 5) & 7) << 2); }

// ---------------- Kernel 1: W_b cast to bf16 (row-major) ----------------
__global__ __launch_bounds__(256) void k_wt(const float* __restrict__ Wb,
                                            unsigned short* __restrict__ Wbf) {
    int i = blockIdx.x * 256 + threadIdx.x;       // 65536
    Wbf[i] = f2bf(Wb[i]);
}

// ---------------- Kernel 2 (fused): per-batch gather + G = E_b*W_b*E_b^T + softmax + f_w ----
// One block per batch, 512 threads (8 waves), 1 block/CU (160KB LDS exactly).
// PRODUCER/CONSUMER wave split:
//   waves 0-3 (producers): own 64 Wb rows in regs (afr=wfr, 128 VGPR); step s computes
//     H'[all i][32-col strip s] -> Ht[s&1] (16KB, transposed+swizzled store).
//   waves 4-7 (consumers): own 64 G rows in regs (afr=efr, loaded at s==1); step s
//     computes G[rows][strip s-1] from Ht[(s-1)&1] with running rowmax.
//   One barrier per step; P1(s) and P2(s-1) run CONCURRENTLY on each SIMD
//   (independent MFMA+LDS streams = latency hiding without occupancy).
//   Step 0: consumers (idle otherwise) gather E rows 64-255 while producers run P1(0).
// LDS: Es 128KB (swizzled: row r, 16B-chunk c at r*512 + (c*16 ^ ((r&7)<<4)));
//      Ht strips 2x16KB at 128K/144K. Overlays (red2/scratch/fred) reuse Ht after loop.
// All f32->bf16 via v_cvt_pk_bf16_f32. tanh(max)=max(tanh) -> softmax -> f_w from Es.
__global__ __launch_bounds__(512, 2) void k_attn(const int* __restrict__ tok,
                                                 const float* __restrict__ emb,
                                                 const unsigned short* __restrict__ Wbf,
                                                 float* __restrict__ fw) {
    __shared__ __align__(16) char lds[163840];
    char* EsC = lds;                                   // 128KB: swizzled E_b
    float* red2    = (float*)(lds + 131072);           // overlay: 256 f32
    float* scratch = (float*)(lds + 132096);           // overlay: 16 f32
    float* fred    = (float*)(lds + 132160);           // overlay: 16 x 256 f32

    int b = blockIdx.x;
    int tid = threadIdx.x;
    int wid = tid >> 6, ln = tid & 63;
    int l16 = ln & 15, gp = ln >> 4;
    bool prod = (wid < 4);
    const int* tb = tok + (b << 8);

    // afr: producers = 64 Wb rows (A for P1); consumers = 64 E rows (A for P2, loaded s==1)
    short8 afr[8][4];
    if (prod) {
        int r0 = wid << 6;
#pragma unroll
        for (int k = 0; k < 8; k++)
#pragma unroll
            for (int rf = 0; rf < 4; rf++)
                afr[k][rf] = *(const short8*)(Wbf + ((r0 + rf * 16 + l16) << 8) + k * 32 + gp * 8);
    }

    // ---- prologue gather: rows 0..63 (all 512 threads, 4 its) ----
#pragma unroll
    for (int it = 0; it < 4; it++) {
        int c = it * 512 + tid;
        int row = c >> 5, c16 = c & 31;
        const float4* src = (const float4*)(emb + ((size_t)tb[row] << 8) + (c16 << 3));
        short8 o = pack8c(src[0], src[1]);
        *(short8*)(EsC + ((row << 9) | ((c16 << 4) ^ ((row & 7) << 4)))) = o;
    }
    __syncthreads();

    float rmax[16];
#pragma unroll
    for (int i = 0; i < 16; i++) rmax[i] = -1e30f;

    for (int s = 0; s <= 8; s++) {
        if (prod) {
            if (s < 8) {
                // ---- P1(s): H'[rows wid*64..+64][cols s*32..+32] -> Ht[s&1] ----
                char* Ht = lds + 131072 + ((s & 1) << 14);
                f32x4 acc[4][2] = {};
#pragma unroll
                for (int k0 = 0; k0 < 256; k0 += 32) {
                    int kk2 = (k0 + gp * 8) * 2;
                    short8 bfr[2];
#pragma unroll
                    for (int cf = 0; cf < 2; cf++) {
                        int jg = s * 32 + cf * 16 + l16;
                        bfr[cf] = *(const short8*)(EsC + ((jg << 9) | (kk2 ^ ((jg & 7) << 4))));
                    }
                    int ks = k0 >> 5;
                    __builtin_amdgcn_s_setprio(1);
#pragma unroll
                    for (int rf = 0; rf < 4; rf++)
#pragma unroll
                        for (int cf = 0; cf < 2; cf++)
                            acc[rf][cf] = __builtin_amdgcn_mfma_f32_16x16x32_bf16(
                                afr[ks][rf], bfr[cf], acc[rf][cf], 0, 0, 0);
                    __builtin_amdgcn_s_setprio(0);
                }
                // store transposed: H'[i][j] -> Ht[j-local][i], 8B packs, swizzled
#pragma unroll
                for (int rf = 0; rf < 4; rf++)
#pragma unroll
                    for (int cf = 0; cf < 2; cf++) {
                        int i = (wid << 6) + rf * 16 + gp * 4;
                        int jl = cf * 16 + l16;
                        unsigned long long pk =
                            ((unsigned long long)cvtpk(acc[rf][cf][2], acc[rf][cf][3]) << 32)
                            | cvtpk(acc[rf][cf][0], acc[rf][cf][1]);
                        *(unsigned long long*)(Ht + ((jl << 9) | ((i * 2) ^ ((jl & 7) << 4)))) = pk;
                    }
            }
        } else {
            if (s == 0) {
                // ---- consumers gather rows 64..255 (192 rows, 24 its of 256 thr) ----
                int t4 = tid - 256;
#pragma unroll
                for (int it = 0; it < 24; it++) {
                    int c = it * 256 + t4;
                    int row = 64 + (c >> 5), c16 = c & 31;
                    const float4* src = (const float4*)(emb + ((size_t)tb[row] << 8) + (c16 << 3));
                    short8 o = pack8c(src[0], src[1]);
                    *(short8*)(EsC + ((row << 9) | ((c16 << 4) ^ ((row & 7) << 4)))) = o;
                }
            } else {
                if (s == 1) {
                    // afr = E rows [(wid-4)*64, +64) from LDS (all rows now resident)
                    int r0 = (wid - 4) << 6;
#pragma unroll
                    for (int k = 0; k < 8; k++)
#pragma unroll
                        for (int rf = 0; rf < 4; rf++) {
                            int l = r0 + rf * 16 + l16;
                            afr[k][rf] = *(const short8*)(EsC +
                                ((l << 9) | ((k * 64 + gp * 16) ^ ((l & 7) << 4))));
                        }
                }
                // ---- P2(s-1): G[rows][cols (s-1)*32..+32] from Ht[(s-1)&1]; rowmax ----
                char* Ht = lds + 131072 + (((s - 1) & 1) << 14);
                f32x4 acc[4][2] = {};
#pragma unroll
                for (int k0 = 0; k0 < 256; k0 += 32) {
                    int kk2 = (k0 + gp * 8) * 2;
                    short8 bb[2];
#pragma unroll
                    for (int cf = 0; cf < 2; cf++) {
                        int m = cf * 16 + l16;
                        bb[cf] = *(const short8*)(Ht + ((m << 9) | (kk2 ^ ((m & 7) << 4))));
                    }
                    int ks = k0 >> 5;
                    __builtin_amdgcn_s_setprio(1);
#pragma unroll
                    for (int rf = 0; rf < 4; rf++)
#pragma unroll
                        for (int cf = 0; cf < 2; cf++)
                            acc[rf][cf] = __builtin_amdgcn_mfma_f32_16x16x32_bf16(
                                afr[ks][rf], bb[cf], acc[rf][cf], 0, 0, 0);
                    __builtin_amdgcn_s_setprio(0);
                }
#pragma unroll
                for (int rf = 0; rf < 4; rf++)
#pragma unroll
                    for (int r = 0; r < 4; r++)
                        rmax[rf * 4 + r] = fmaxf(rmax[rf * 4 + r],
                                                 fmaxf(acc[rf][0][r], acc[rf][1][r]));
            }
        }
        __syncthreads();
    }

    // ---- consumers publish rowmax to red2 (overlay on Ht0, dead after loop) ----
    if (!prod) {
#pragma unroll
        for (int i = 0; i < 16; i++) {
            float v = rmax[i];
            v = fmaxf(v, __shfl_xor(v, 1));
            v = fmaxf(v, __shfl_xor(v, 2));
            v = fmaxf(v, __shfl_xor(v, 4));
            v = fmaxf(v, __shfl_xor(v, 8));
            rmax[i] = v;
        }
        if (l16 == 0) {
            int r0 = (wid - 4) << 6;
#pragma unroll
            for (int rf = 0; rf < 4; rf++)
#pragma unroll
                for (int r = 0; r < 4; r++)
                    red2[r0 + rf * 16 + gp * 4 + r] = rmax[rf * 4 + r];
        }
    }
    __syncthreads();

    // ---- tanh + softmax over the 256 row-maxima ----
    float x = -1e30f;
    if (tid < 256) x = tanhf(red2[tid]);
    float mx = x;
#pragma unroll
    for (int s = 1; s < 64; s <<= 1) mx = fmaxf(mx, __shfl_xor(mx, s));
    if (ln == 0) scratch[wid] = mx;
    __syncthreads();
    float bm = scratch[0];
#pragma unroll
    for (int i = 1; i < 8; i++) bm = fmaxf(bm, scratch[i]);
    float e = (tid < 256) ? expf(x - bm) : 0.f;
    float sm = e;
#pragma unroll
    for (int s = 1; s < 64; s <<= 1) sm += __shfl_xor(sm, s);
    if (ln == 0) scratch[8 + wid] = sm;
    __syncthreads();
    float tot = 0.f;
#pragma unroll
    for (int i = 0; i < 8; i++) tot += scratch[8 + i];
    if (tid < 256) red2[tid] = e / tot;    // aq
    __syncthreads();

    // ---- f_w[d] = sum_l aq[l] * E_b[l][d]  (E from LDS, partials in fred, bank-swizzled) ----
    {
        int g = tid >> 5;                    // 0..15 -> l-range [16g, 16g+16)
        int d0 = (tid & 31) << 3;            // 8 d's per thread
        float s0[8] = {0.f, 0.f, 0.f, 0.f, 0.f, 0.f, 0.f, 0.f};
        int lbase = g << 4;
#pragma unroll
        for (int li = 0; li < 16; li++) {
            int l = lbase + li;
            float aql = red2[l];
            int byt = (l << 9) | ((d0 * 2) ^ ((l & 7) << 4));
            short8 v = *(const short8*)(EsC + byt);
#pragma unroll
            for (int jj = 0; jj < 8; jj++)
                s0[jj] += aql * bf2f((unsigned short)v[jj]);
        }
        f32x4 w0, w1;
        w0[0] = s0[0]; w0[1] = s0[1]; w0[2] = s0[2]; w0[3] = s0[3];
        w1[0] = s0[4]; w1[1] = s0[5]; w1[2] = s0[6]; w1[3] = s0[7];
        *(f32x4*)(fred + g * 256 + fsw(d0)) = w0;
        *(f32x4*)(fred + g * 256 + fsw(d0 + 4)) = w1;
    }
    __syncthreads();
    if (tid < 256) {
        float f = 0.f;
        int dw = fsw(tid);
#pragma unroll
        for (int g2 = 0; g2 < 16; g2++) f += fred[g2 * 256 + dw];
        fw[(b << 8) + tid] = f;
    }
}

// ---------------- Kernel 3: out = f_w @ lin_w^T + lin_b  (fp32 tiled GEMM) ----------------
// Tile 32(M)x64(N), 256 blocks (full CU coverage), float4 staging.
__global__ __launch_bounds__(256) void k_out(const float* __restrict__ fw,
                                             const float* __restrict__ lw,
                                             const float* __restrict__ lb,
                                             float* __restrict__ out) {
    __shared__ float As[32][68];
    __shared__ float Bs[64][65];
    int tid = threadIdx.x;
    int tx = tid & 15, ty = tid >> 4;
    int r0 = blockIdx.y * 32, n0 = blockIdx.x * 64;
    float acc[2][4] = {};
    for (int k0 = 0; k0 < 256; k0 += 64) {
        __syncthreads();
#pragma unroll
        for (int it = 0; it < 2; it++) {
            int idx = it * 256 + tid;
            int i = idx >> 4, k4 = (idx & 15) << 2;
            *(float4*)&As[i][k4] = *(const float4*)&fw[(r0 + i) * 256 + k0 + k4];
        }
#pragma unroll
        for (int it = 0; it < 4; it++) {
            int idx = it * 256 + tid;
            int n = idx >> 4, k4 = (idx & 15) << 2;
            int nn = n0 + n;
            float4 v = {0.f, 0.f, 0.f, 0.f};
            if (nn < O_) v = *(const float4*)&lw[(size_t)nn * 256 + k0 + k4];
            Bs[k4][n] = v.x; Bs[k4 + 1][n] = v.y; Bs[k4 + 2][n] = v.z; Bs[k4 + 3][n] = v.w;
        }
        __syncthreads();
#pragma unroll
        for (int k = 0; k < 64; k++) {
            float a0 = As[ty * 2][k], a1 = As[ty * 2 + 1][k];
            float b0 = Bs[k][tx * 4], b1 = Bs[k][tx * 4 + 1];
            float b2 = Bs[k][tx * 4 + 2], b3 = Bs[k][tx * 4 + 3];
            acc[0][0] += a0 * b0; acc[0][1] += a0 * b1; acc[0][2] += a0 * b2; acc[0][3] += a0 * b3;
            acc[1][0] += a1 * b0; acc[1][1] += a1 * b1; acc[1][2] += a1 * b2; acc[1][3] += a1 * b3;
        }
    }
#pragma unroll
    for (int i = 0; i < 2; i++)
#pragma unroll
        for (int j = 0; j < 4; j++) {
            int n = n0 + tx * 4 + j;
            if (n < O_) out[(size_t)(r0 + ty * 2 + i) * O_ + n] = acc[i][j] + lb[n];
        }
}

extern "C" void kernel_launch(void* const* d_in, const int* in_sizes, int n_in,
                              void* d_out, int out_size, void* d_ws, size_t ws_size,
                              hipStream_t stream) {
    const int* tok = (const int*)d_in[0];
    const float* emb = (const float*)d_in[1];
    const float* Wb = (const float*)d_in[2];
    const float* lw = (const float*)d_in[3];
    const float* lb = (const float*)d_in[4];
    float* out = (float*)d_out;

    char* ws = (char*)d_ws;
    unsigned short* Wbf = (unsigned short*)(ws);            // 131,072 B
    float*          fwp = (float*)(ws + 131072);            // 524,288 B

    hipLaunchKernelGGL(k_wt,   dim3(256),    dim3(256), 0, stream, Wb, Wbf);
    hipLaunchKernelGGL(k_attn, dim3(512),    dim3(512), 0, stream, tok, emb, Wbf, fwp);
    hipLaunchKernelGGL(k_out,  dim3(16, 16), dim3(256), 0, stream, fwp, lw, lb, out);
}

// Round 11
// 79.169 us; speedup vs baseline: 3.7794x; 3.7794x over previous
//
#include <hip/hip_runtime.h>
#include <hip/hip_bf16.h>
#include <math.h>

// Problem constants
#define B_ 512
#define L_ 256
#define D_ 256
#define V_ 100000
#define O_ 1000

typedef __attribute__((ext_vector_type(8))) short short8;
typedef __attribute__((ext_vector_type(4))) float f32x4;

static __device__ __forceinline__ unsigned short f2bf(float f) {
    union { float f; unsigned u; } v; v.f = f;
    unsigned r = v.u + 0x7FFFu + ((v.u >> 16) & 1u);   // RNE (inputs are finite)
    return (unsigned short)(r >> 16);
}
static __device__ __forceinline__ float bf2f(unsigned short u) {
    union { unsigned u; float f; } v; v.u = ((unsigned)u) << 16;
    return v.f;
}
static __device__ __forceinline__ short8 pack8(float4 a, float4 c) {
    short8 o;
    o[0] = (short)f2bf(a.x); o[1] = (short)f2bf(a.y);
    o[2] = (short)f2bf(a.z); o[3] = (short)f2bf(a.w);
    o[4] = (short)f2bf(c.x); o[5] = (short)f2bf(c.y);
    o[6] = (short)f2bf(c.z); o[7] = (short)f2bf(c.w);
    return o;
}
// fred bank-spread swizzle (valid as fsw(base)+j, j<4, base%4==0)
static __device__ __forceinline__ int fsw(int d) { return d ^ (((d >> 5) & 7) << 2); }

// ---------------- Kernel 1: W_b cast to bf16 (row-major) ----------------
__global__ __launch_bounds__(256) void k_wt(const float* __restrict__ Wb,
                                            unsigned short* __restrict__ Wbf) {
    int i = blockIdx.x * 256 + threadIdx.x;       // 65536
    Wbf[i] = f2bf(Wb[i]);
}

// ---------------- Kernel 2 (fused): per-batch gather + G = E_b*W_b*E_b^T + softmax + f_w ----
// One block per batch, 512 threads (8 waves), 1 block/CU (160KB LDS exactly).
// SAME-WAVE SOFTWARE PIPELINE over 8 column-strips of 32:
//   Ht strips: 2 x 16KB (double-buffered). Step s (1..7) fuses in ONE k-loop:
//     P1(s):  H'[rows i0..i0+32][strip s] from (wfr regs x Es)      -> HtW = Ht[s&1]
//     P2(s-1): G[rows i0..i0+32][strip s-1] from (efr regs x HtR)   -> running rowmax
//   Two independent MFMA+LDS streams per wave => each stream's ds_read latency hides
//   under the other's MFMAs (no wave-role divergence, no register blowup - round-10 lesson).
//   Step 0 = P1(0) with round-9's split gather overlapped; step 8 = P2(7) epilogue.
// Es swizzle: row r, 16B-chunk c at r*512 + (c*16 ^ ((r&7)<<4)). One barrier per step.
// tanh(max)=max(tanh) -> softmax over L -> f_w = a^T E (from Es; fred bank-swizzled).
__global__ __launch_bounds__(512, 2) void k_attn(const int* __restrict__ tok,
                                                 const float* __restrict__ emb,
                                                 const unsigned short* __restrict__ Wbf,
                                                 float* __restrict__ fw) {
    __shared__ __align__(16) char lds[163840];
    char* EsC = lds;                                   // 128KB: swizzled E_b
    float* red2    = (float*)(lds + 131072);           // overlay: 256 f32 (on Ht0, post-loop)
    float* scratch = (float*)(lds + 132096);           // overlay: 16 f32
    float* fred    = (float*)(lds + 132160);           // overlay: 16 x 256 f32

    int b = blockIdx.x;
    int tid = threadIdx.x;
    int wid = tid >> 6, ln = tid & 63;
    int l16 = ln & 15, gp = ln >> 4;
    int i0 = wid * 32;          // wave's Wb-row block (P1) / G-row block (P2)
    const int* tb = tok + (b << 8);

    // ---- Wb A-frag preload (global, L2-hot): rows [i0, i0+32) -> 64 VGPR ----
    short8 wfr[8][2];
#pragma unroll
    for (int k = 0; k < 8; k++)
#pragma unroll
        for (int rf = 0; rf < 2; rf++)
            wfr[k][rf] = *(const short8*)(Wbf + ((i0 + rf * 16 + l16) << 8) + k * 32 + gp * 8);

    // ---- gather chunk 0 (rows 0..63) ----
#pragma unroll
    for (int it = 0; it < 4; it++) {
        int c = it * 512 + tid;
        int row = c >> 5, c16 = c & 31;
        const float4* src = (const float4*)(emb + ((size_t)tb[row] << 8) + (c16 << 3));
        short8 o = pack8(src[0], src[1]);
        *(short8*)(EsC + ((row << 9) | ((c16 << 4) ^ ((row & 7) << 4)))) = o;
    }
    __syncthreads();   // barrier A: rows 0-63 visible

    // ---- issue loads for rows 64..159 into regs; land after P1(0) ----
    float4 ga[6], gb[6];
#pragma unroll
    for (int it = 0; it < 6; it++) {
        int c = (it + 4) * 512 + tid;
        int row = c >> 5, c16 = c & 31;
        const float4* src = (const float4*)(emb + ((size_t)tb[row] << 8) + (c16 << 3));
        ga[it] = src[0]; gb[it] = src[1];
    }

    float rmax[8];
#pragma unroll
    for (int i = 0; i < 8; i++) rmax[i] = -1e30f;

    // ---- P1-only strip (step 0) ----
    auto P1strip = [&](int s, char* HtW) {
        f32x4 acc[2][2] = {};
#pragma unroll
        for (int k0 = 0; k0 < 256; k0 += 32) {
            int kk2 = (k0 + gp * 8) * 2;
            short8 b1[2];
#pragma unroll
            for (int cf = 0; cf < 2; cf++) {
                int jg = s * 32 + cf * 16 + l16;
                b1[cf] = *(const short8*)(EsC + ((jg << 9) | (kk2 ^ ((jg & 7) << 4))));
            }
            int ks = k0 >> 5;
            __builtin_amdgcn_s_setprio(1);
#pragma unroll
            for (int rf = 0; rf < 2; rf++)
#pragma unroll
                for (int cf = 0; cf < 2; cf++)
                    acc[rf][cf] = __builtin_amdgcn_mfma_f32_16x16x32_bf16(
                        wfr[ks][rf], b1[cf], acc[rf][cf], 0, 0, 0);
            __builtin_amdgcn_s_setprio(0);
        }
#pragma unroll
        for (int rf = 0; rf < 2; rf++)
#pragma unroll
            for (int cf = 0; cf < 2; cf++) {
                int i = i0 + rf * 16 + gp * 4;
                int jl = cf * 16 + l16;
                unsigned long long pk;
                unsigned short* p = (unsigned short*)&pk;
                p[0] = f2bf(acc[rf][cf][0]);
                p[1] = f2bf(acc[rf][cf][1]);
                p[2] = f2bf(acc[rf][cf][2]);
                p[3] = f2bf(acc[rf][cf][3]);
                *(unsigned long long*)(HtW + ((jl << 9) | ((i * 2) ^ ((jl & 7) << 4)))) = pk;
            }
    };

    short8 efr[8][2];
    // ---- P2-only strip (step 8 epilogue) ----
    auto P2strip = [&](char* HtR) {
        f32x4 acc[2][2] = {};
#pragma unroll
        for (int k0 = 0; k0 < 256; k0 += 32) {
            int kk2 = (k0 + gp * 8) * 2;
            short8 b2[2];
#pragma unroll
            for (int cf = 0; cf < 2; cf++) {
                int m = cf * 16 + l16;
                b2[cf] = *(const short8*)(HtR + ((m << 9) | (kk2 ^ ((m & 7) << 4))));
            }
            int ks = k0 >> 5;
            __builtin_amdgcn_s_setprio(1);
#pragma unroll
            for (int rf = 0; rf < 2; rf++)
#pragma unroll
                for (int cf = 0; cf < 2; cf++)
                    acc[rf][cf] = __builtin_amdgcn_mfma_f32_16x16x32_bf16(
                        efr[ks][rf], b2[cf], acc[rf][cf], 0, 0, 0);
            __builtin_amdgcn_s_setprio(0);
        }
#pragma unroll
        for (int rf = 0; rf < 2; rf++)
#pragma unroll
            for (int r = 0; r < 4; r++)
                rmax[rf * 4 + r] = fmaxf(rmax[rf * 4 + r],
                                         fmaxf(acc[rf][0][r], acc[rf][1][r]));
    };

    // ---- step 0: P1(0) -> Ht0, with gather overlap ----
    P1strip(0, lds + 131072);

    // land rows 64..159 (P1(0) read only rows 0-31; disjoint)
#pragma unroll
    for (int it = 0; it < 6; it++) {
        int c = (it + 4) * 512 + tid;
        int row = c >> 5, c16 = c & 31;
        short8 o = pack8(ga[it], gb[it]);
        *(short8*)(EsC + ((row << 9) | ((c16 << 4) ^ ((row & 7) << 4)))) = o;
    }
    // gather rows 160..255
#pragma unroll
    for (int it = 10; it < 16; it++) {
        int c = it * 512 + tid;
        int row = c >> 5, c16 = c & 31;
        const float4* src = (const float4*)(emb + ((size_t)tb[row] << 8) + (c16 << 3));
        short8 o = pack8(src[0], src[1]);
        *(short8*)(EsC + ((row << 9) | ((c16 << 4) ^ ((row & 7) << 4)))) = o;
    }
    __syncthreads();   // barrier B: all E rows + Ht0 visible

    // ---- E A-frag preload (from LDS): rows [i0, i0+32) -> 64 VGPR ----
#pragma unroll
    for (int k = 0; k < 8; k++)
#pragma unroll
        for (int rf = 0; rf < 2; rf++) {
            int l = i0 + rf * 16 + l16;
            efr[k][rf] = *(const short8*)(EsC + ((l << 9) | ((k * 64 + gp * 16) ^ ((l & 7) << 4))));
        }

    // ---- steps 1..7: fused P1(s) || P2(s-1), one barrier per step ----
    for (int s = 1; s < 8; s++) {
        char* HtW = lds + 131072 + ((s & 1) << 14);
        char* HtR = lds + 131072 + (((s - 1) & 1) << 14);
        f32x4 a1[2][2] = {};
        f32x4 a2[2][2] = {};
#pragma unroll
        for (int k0 = 0; k0 < 256; k0 += 32) {
            int kk2 = (k0 + gp * 8) * 2;
            short8 b1[2], b2[2];
#pragma unroll
            for (int cf = 0; cf < 2; cf++) {
                int jg = s * 32 + cf * 16 + l16;
                b1[cf] = *(const short8*)(EsC + ((jg << 9) | (kk2 ^ ((jg & 7) << 4))));
                int m = cf * 16 + l16;
                b2[cf] = *(const short8*)(HtR + ((m << 9) | (kk2 ^ ((m & 7) << 4))));
            }
            int ks = k0 >> 5;
            __builtin_amdgcn_s_setprio(1);
#pragma unroll
            for (int rf = 0; rf < 2; rf++)
#pragma unroll
                for (int cf = 0; cf < 2; cf++) {
                    a1[rf][cf] = __builtin_amdgcn_mfma_f32_16x16x32_bf16(
                        wfr[ks][rf], b1[cf], a1[rf][cf], 0, 0, 0);
                    a2[rf][cf] = __builtin_amdgcn_mfma_f32_16x16x32_bf16(
                        efr[ks][rf], b2[cf], a2[rf][cf], 0, 0, 0);
                }
            __builtin_amdgcn_s_setprio(0);
        }
        // store Ht strip s
#pragma unroll
        for (int rf = 0; rf < 2; rf++)
#pragma unroll
            for (int cf = 0; cf < 2; cf++) {
                int i = i0 + rf * 16 + gp * 4;
                int jl = cf * 16 + l16;
                unsigned long long pk;
                unsigned short* p = (unsigned short*)&pk;
                p[0] = f2bf(a1[rf][cf][0]);
                p[1] = f2bf(a1[rf][cf][1]);
                p[2] = f2bf(a1[rf][cf][2]);
                p[3] = f2bf(a1[rf][cf][3]);
                *(unsigned long long*)(HtW + ((jl << 9) | ((i * 2) ^ ((jl & 7) << 4)))) = pk;
            }
        // rowmax from P2(s-1)
#pragma unroll
        for (int rf = 0; rf < 2; rf++)
#pragma unroll
            for (int r = 0; r < 4; r++)
                rmax[rf * 4 + r] = fmaxf(rmax[rf * 4 + r],
                                         fmaxf(a2[rf][0][r], a2[rf][1][r]));
        __syncthreads();
    }

    // ---- step 8: P2(7) from Ht1 ----
    P2strip(lds + 131072 + (1 << 14));

    // ---- reduce rowmax across l16 lanes, publish to red2 ----
#pragma unroll
    for (int i = 0; i < 8; i++) {
        float v = rmax[i];
        v = fmaxf(v, __shfl_xor(v, 1));
        v = fmaxf(v, __shfl_xor(v, 2));
        v = fmaxf(v, __shfl_xor(v, 4));
        v = fmaxf(v, __shfl_xor(v, 8));
        rmax[i] = v;
    }
    __syncthreads();   // Ht0 dead; red2 overlay safe
    if (l16 == 0) {
#pragma unroll
        for (int rf = 0; rf < 2; rf++)
#pragma unroll
            for (int r = 0; r < 4; r++)
                red2[i0 + rf * 16 + gp * 4 + r] = rmax[rf * 4 + r];
    }
    __syncthreads();

    // ---- tanh + softmax over the 256 row-maxima ----
    float x = -1e30f;
    if (tid < 256) x = tanhf(red2[tid]);
    float mx = x;
#pragma unroll
    for (int s = 1; s < 64; s <<= 1) mx = fmaxf(mx, __shfl_xor(mx, s));
    if (ln == 0) scratch[wid] = mx;
    __syncthreads();
    float bm = scratch[0];
#pragma unroll
    for (int i = 1; i < 8; i++) bm = fmaxf(bm, scratch[i]);
    float e = (tid < 256) ? expf(x - bm) : 0.f;
    float sm = e;
#pragma unroll
    for (int s = 1; s < 64; s <<= 1) sm += __shfl_xor(sm, s);
    if (ln == 0) scratch[8 + wid] = sm;
    __syncthreads();
    float tot = 0.f;
#pragma unroll
    for (int i = 0; i < 8; i++) tot += scratch[8 + i];
    if (tid < 256) red2[tid] = e / tot;    // aq
    __syncthreads();

    // ---- f_w[d] = sum_l aq[l] * E_b[l][d]  (E from LDS, partials in fred, bank-swizzled) ----
    {
        int g = tid >> 5;                    // 0..15 -> l-range [16g, 16g+16)
        int d0 = (tid & 31) << 3;            // 8 d's per thread
        float s0[8] = {0.f, 0.f, 0.f, 0.f, 0.f, 0.f, 0.f, 0.f};
        int lbase = g << 4;
#pragma unroll
        for (int li = 0; li < 16; li++) {
            int l = lbase + li;
            float aql = red2[l];
            int byt = (l << 9) | ((d0 * 2) ^ ((l & 7) << 4));
            short8 v = *(const short8*)(EsC + byt);
#pragma unroll
            for (int jj = 0; jj < 8; jj++)
                s0[jj] += aql * bf2f((unsigned short)v[jj]);
        }
        f32x4 w0, w1;
        w0[0] = s0[0]; w0[1] = s0[1]; w0[2] = s0[2]; w0[3] = s0[3];
        w1[0] = s0[4]; w1[1] = s0[5]; w1[2] = s0[6]; w1[3] = s0[7];
        *(f32x4*)(fred + g * 256 + fsw(d0)) = w0;
        *(f32x4*)(fred + g * 256 + fsw(d0 + 4)) = w1;
    }
    __syncthreads();
    if (tid < 256) {
        float f = 0.f;
        int dw = fsw(tid);
#pragma unroll
        for (int g2 = 0; g2 < 16; g2++) f += fred[g2 * 256 + dw];
        fw[(b << 8) + tid] = f;
    }
}

// ---------------- Kernel 3: out = f_w @ lin_w^T + lin_b  (fp32 tiled GEMM) ----------------
// Tile 32(M)x64(N), 256 blocks (full CU coverage), float4 staging.
__global__ __launch_bounds__(256) void k_out(const float* __restrict__ fw,
                                             const float* __restrict__ lw,
                                             const float* __restrict__ lb,
                                             float* __restrict__ out) {
    __shared__ float As[32][68];
    __shared__ float Bs[64][65];
    int tid = threadIdx.x;
    int tx = tid & 15, ty = tid >> 4;
    int r0 = blockIdx.y * 32, n0 = blockIdx.x * 64;
    float acc[2][4] = {};
    for (int k0 = 0; k0 < 256; k0 += 64) {
        __syncthreads();
#pragma unroll
        for (int it = 0; it < 2; it++) {
            int idx = it * 256 + tid;
            int i = idx >> 4, k4 = (idx & 15) << 2;
            *(float4*)&As[i][k4] = *(const float4*)&fw[(r0 + i) * 256 + k0 + k4];
        }
#pragma unroll
        for (int it = 0; it < 4; it++) {
            int idx = it * 256 + tid;
            int n = idx >> 4, k4 = (idx & 15) << 2;
            int nn = n0 + n;
            float4 v = {0.f, 0.f, 0.f, 0.f};
            if (nn < O_) v = *(const float4*)&lw[(size_t)nn * 256 + k0 + k4];
            Bs[k4][n] = v.x; Bs[k4 + 1][n] = v.y; Bs[k4 + 2][n] = v.z; Bs[k4 + 3][n] = v.w;
        }
        __syncthreads();
#pragma unroll
        for (int k = 0; k < 64; k++) {
            float a0 = As[ty * 2][k], a1 = As[ty * 2 + 1][k];
            float b0 = Bs[k][tx * 4], b1 = Bs[k][tx * 4 + 1];
            float b2 = Bs[k][tx * 4 + 2], b3 = Bs[k][tx * 4 + 3];
            acc[0][0] += a0 * b0; acc[0][1] += a0 * b1; acc[0][2] += a0 * b2; acc[0][3] += a0 * b3;
            acc[1][0] += a1 * b0; acc[1][1] += a1 * b1; acc[1][2] += a1 * b2; acc[1][3] += a1 * b3;
        }
    }
#pragma unroll
    for (int i = 0; i < 2; i++)
#pragma unroll
        for (int j = 0; j < 4; j++) {
            int n = n0 + tx * 4 + j;
            if (n < O_) out[(size_t)(r0 + ty * 2 + i) * O_ + n] = acc[i][j] + lb[n];
        }
}

extern "C" void kernel_launch(void* const* d_in, const int* in_sizes, int n_in,
                              void* d_out, int out_size, void* d_ws, size_t ws_size,
                              hipStream_t stream) {
    const int* tok = (const int*)d_in[0];
    const float* emb = (const float*)d_in[1];
    const float* Wb = (const float*)d_in[2];
    const float* lw = (const float*)d_in[3];
    const float* lb = (const float*)d_in[4];
    float* out = (float*)d_out;

    char* ws = (char*)d_ws;
    unsigned short* Wbf = (unsigned short*)(ws);            // 131,072 B
    float*          fwp = (float*)(ws + 131072);            // 524,288 B

    hipLaunchKernelGGL(k_wt,   dim3(256),    dim3(256), 0, stream, Wb, Wbf);
    hipLaunchKernelGGL(k_attn, dim3(512),    dim3(512), 0, stream, tok, emb, Wbf, fwp);
    hipLaunchKernelGGL(k_out,  dim3(16, 16), dim3(256), 0, stream, fwp, lw, lb, out);
}